// Round 3
// baseline (144.707 us; speedup 1.0000x reference)
//
#include <hip/hip_runtime.h>
#include <hip/hip_bf16.h>
#include <cstdint>

#define NBATCH 4
#define NNODE  2048
#define NEDGE  8192
#define ETOT   (NBATCH * NEDGE)   // 32768 edges total
#define NTOT   (NBATCH * NNODE)   // 8192 nodes total

__device__ __forceinline__ float elu(float x) {
    return x > 0.0f ? x : expm1f(x);
}

// ---------------------------------------------------------------------------
// Kernel 1: scan the dense one-hot Ro/Ri matrices (f32), extract the column
// index of the single 1.0 per row. Restructured for MLP: two uniform loops
// (no per-iter base select), 4 independent uint4 loads per outer iteration,
// single OR-reduced rare-path test. Also zeroes the scatter accumulator A.
// Launch: grid chosen so nth = 2^20; chunks/matrix = 2^24 -> 4 outer iters.
// ---------------------------------------------------------------------------
__global__ void in_idx_kernel(const uint4* __restrict__ Ro,
                              const uint4* __restrict__ Ri,
                              int* __restrict__ ro_idx,
                              int* __restrict__ ri_idx,
                              float* __restrict__ A, int a_elems) {
    const int tid = blockIdx.x * blockDim.x + threadIdx.x;
    const int nth = gridDim.x * blockDim.x;          // 2^20

    for (int i = tid; i < a_elems; i += nth) A[i] = 0.0f;

    const int chunks = ETOT * (NNODE / 4);           // 2^24 per matrix

    #pragma unroll
    for (int m = 0; m < 2; ++m) {
        const uint4* __restrict__ src = m ? Ri : Ro;
        int* __restrict__ dst = m ? ri_idx : ro_idx;
        for (int base = tid; base < chunks; base += 4 * nth) {
            // 4 independent loads in flight
            const uint4 v0 = src[base];
            const uint4 v1 = src[base + nth];
            const uint4 v2 = src[base + 2 * nth];
            const uint4 v3 = src[base + 3 * nth];
            const uint32_t o0 = v0.x | v0.y | v0.z | v0.w;
            const uint32_t o1 = v1.x | v1.y | v1.z | v1.w;
            const uint32_t o2 = v2.x | v2.y | v2.z | v2.w;
            const uint32_t o3 = v3.x | v3.y | v3.z | v3.w;
            if ((o0 | o1 | o2 | o3) == 0u) continue;
            // rare path: ~1/128 of iterations
            const uint4  vs[4] = {v0, v1, v2, v3};
            const uint32_t os[4] = {o0, o1, o2, o3};
            #pragma unroll
            for (int u = 0; u < 4; ++u) {
                if (os[u] == 0u) continue;
                const int cc = base + u * nth;
                const uint32_t w[4] = {vs[u].x, vs[u].y, vs[u].z, vs[u].w};
                #pragma unroll
                for (int k = 0; k < 4; ++k) {
                    if (w[k] != 0u) {
                        const int pos = cc * 4 + k;          // flat f32 index (< 2^26)
                        dst[pos >> 11] = pos & (NNODE - 1);
                    }
                }
            }
        }
    }
}

// ---------------------------------------------------------------------------
// Kernel 2: per-edge phi_R1 (10->8->8->8->4, ELU) + scatter-add into A.
// ---------------------------------------------------------------------------
__global__ void in_edge1_kernel(const float* __restrict__ X,    // [B,3,N]
                                const float* __restrict__ Ra,   // [B,E,4]
                                const int* __restrict__ ro_idx,
                                const int* __restrict__ ri_idx,
                                const float* __restrict__ W1, const float* __restrict__ b1,
                                const float* __restrict__ W2, const float* __restrict__ b2,
                                const float* __restrict__ W3, const float* __restrict__ b3,
                                const float* __restrict__ W4, const float* __restrict__ b4,
                                float* __restrict__ Eff,       // [B*E,4]
                                float* __restrict__ A) {       // [B*N,4]
    __shared__ float sW1[80], sb1[8], sW2[64], sb2[8], sW3[64], sb3[8], sW4[32], sb4[4];
    const int t = threadIdx.x, bs = blockDim.x;
    for (int i = t; i < 80; i += bs) sW1[i] = W1[i];
    for (int i = t; i < 8;  i += bs) sb1[i] = b1[i];
    for (int i = t; i < 64; i += bs) sW2[i] = W2[i];
    for (int i = t; i < 8;  i += bs) sb2[i] = b2[i];
    for (int i = t; i < 64; i += bs) sW3[i] = W3[i];
    for (int i = t; i < 8;  i += bs) sb3[i] = b3[i];
    for (int i = t; i < 32; i += bs) sW4[i] = W4[i];
    for (int i = t; i < 4;  i += bs) sb4[i] = b4[i];
    __syncthreads();

    const int e = blockIdx.x * blockDim.x + threadIdx.x;
    if (e >= ETOT) return;
    const int b  = e >> 13;                       // / NEDGE
    const int ro = ro_idx[e] & (NNODE - 1);       // mask: garbage -> wrong, not fault
    const int ri = ri_idx[e] & (NNODE - 1);

    float x[10];
    const float* Xb = X + (long)b * 3 * NNODE;
    #pragma unroll
    for (int d = 0; d < 3; ++d) x[d]     = Xb[d * NNODE + ro];  // Xi (receiver)
    #pragma unroll
    for (int d = 0; d < 3; ++d) x[3 + d] = Xb[d * NNODE + ri];  // Xo (sender)
    const float4 ra = ((const float4*)Ra)[e];
    x[6] = ra.x; x[7] = ra.y; x[8] = ra.z; x[9] = ra.w;

    float h1[8], h2[8], h3[8];
    #pragma unroll
    for (int j = 0; j < 8; ++j) {
        float s = sb1[j];
        #pragma unroll
        for (int i = 0; i < 10; ++i) s += x[i] * sW1[i * 8 + j];
        h1[j] = elu(s);
    }
    #pragma unroll
    for (int j = 0; j < 8; ++j) {
        float s = sb2[j];
        #pragma unroll
        for (int i = 0; i < 8; ++i) s += h1[i] * sW2[i * 8 + j];
        h2[j] = elu(s);
    }
    #pragma unroll
    for (int j = 0; j < 8; ++j) {
        float s = sb3[j];
        #pragma unroll
        for (int i = 0; i < 8; ++i) s += h2[i] * sW3[i * 8 + j];
        h3[j] = elu(s);
    }
    float* Arow = A + ((long)(b * NNODE + ri)) * 4;
    float4 eff;
    float* effp = (float*)&eff;
    #pragma unroll
    for (int j = 0; j < 4; ++j) {
        float s = sb4[j];
        #pragma unroll
        for (int i = 0; i < 8; ++i) s += h3[i] * sW4[i * 4 + j];
        effp[j] = s;
        atomicAdd(&Arow[j], s);
    }
    ((float4*)Eff)[e] = eff;
}

// ---------------------------------------------------------------------------
// Kernel 3: per-node phi_O (7->8->8->3, ELU on hidden).
// ---------------------------------------------------------------------------
__global__ void in_node_kernel(const float* __restrict__ X,     // [B,3,N]
                               const float* __restrict__ A,     // [B*N,4]
                               const float* __restrict__ W1, const float* __restrict__ b1,
                               const float* __restrict__ W2, const float* __restrict__ b2,
                               const float* __restrict__ W3, const float* __restrict__ b3,
                               float* __restrict__ Xtil) {      // [B*N,3]
    __shared__ float sW1[56], sb1[8], sW2[64], sb2[8], sW3[24], sb3[3];
    const int t = threadIdx.x, bs = blockDim.x;
    for (int i = t; i < 56; i += bs) sW1[i] = W1[i];
    for (int i = t; i < 8;  i += bs) sb1[i] = b1[i];
    for (int i = t; i < 64; i += bs) sW2[i] = W2[i];
    for (int i = t; i < 8;  i += bs) sb2[i] = b2[i];
    for (int i = t; i < 24; i += bs) sW3[i] = W3[i];
    for (int i = t; i < 3;  i += bs) sb3[i] = b3[i];
    __syncthreads();

    const int n = blockIdx.x * blockDim.x + threadIdx.x;
    if (n >= NTOT) return;
    const int b  = n >> 11;           // / NNODE
    const int nn = n & (NNODE - 1);

    float c[7];
    const float* Xb = X + (long)b * 3 * NNODE;
    #pragma unroll
    for (int d = 0; d < 3; ++d) c[d] = Xb[d * NNODE + nn];
    const float4 a4 = ((const float4*)A)[n];
    c[3] = a4.x; c[4] = a4.y; c[5] = a4.z; c[6] = a4.w;

    float h1[8], h2[8];
    #pragma unroll
    for (int j = 0; j < 8; ++j) {
        float s = sb1[j];
        #pragma unroll
        for (int i = 0; i < 7; ++i) s += c[i] * sW1[i * 8 + j];
        h1[j] = elu(s);
    }
    #pragma unroll
    for (int j = 0; j < 8; ++j) {
        float s = sb2[j];
        #pragma unroll
        for (int i = 0; i < 8; ++i) s += h1[i] * sW2[i * 8 + j];
        h2[j] = elu(s);
    }
    #pragma unroll
    for (int j = 0; j < 3; ++j) {
        float s = sb3[j];
        #pragma unroll
        for (int i = 0; i < 8; ++i) s += h2[i] * sW3[i * 3 + j];
        Xtil[(long)n * 3 + j] = s;
    }
}

// ---------------------------------------------------------------------------
// Kernel 4: per-edge phi_R2 (10->8->8->8->1, ELU) + sigmoid -> f32 out.
// ---------------------------------------------------------------------------
__global__ void in_edge2_kernel(const float* __restrict__ Xtil,  // [B*N,3]
                                const float* __restrict__ Eff,   // [B*E,4]
                                const int* __restrict__ ro_idx,
                                const int* __restrict__ ri_idx,
                                const float* __restrict__ W1, const float* __restrict__ b1,
                                const float* __restrict__ W2, const float* __restrict__ b2,
                                const float* __restrict__ W3, const float* __restrict__ b3,
                                const float* __restrict__ W4, const float* __restrict__ b4,
                                float* __restrict__ out) {       // [B*E]
    __shared__ float sW1[80], sb1[8], sW2[64], sb2[8], sW3[64], sb3[8], sW4[8], sb4[1];
    const int t = threadIdx.x, bs = blockDim.x;
    for (int i = t; i < 80; i += bs) sW1[i] = W1[i];
    for (int i = t; i < 8;  i += bs) sb1[i] = b1[i];
    for (int i = t; i < 64; i += bs) sW2[i] = W2[i];
    for (int i = t; i < 8;  i += bs) sb2[i] = b2[i];
    for (int i = t; i < 64; i += bs) sW3[i] = W3[i];
    for (int i = t; i < 8;  i += bs) sb3[i] = b3[i];
    for (int i = t; i < 8;  i += bs) sW4[i] = W4[i];
    for (int i = t; i < 1;  i += bs) sb4[i] = b4[i];
    __syncthreads();

    const int e = blockIdx.x * blockDim.x + threadIdx.x;
    if (e >= ETOT) return;
    const int b  = e >> 13;
    const int ro = ro_idx[e] & (NNODE - 1);
    const int ri = ri_idx[e] & (NNODE - 1);

    float x[10];
    const float* Xb = Xtil + (long)b * NNODE * 3;
    #pragma unroll
    for (int d = 0; d < 3; ++d) x[d]     = Xb[(long)ri * 3 + d];   // Xi_t via Ri
    #pragma unroll
    for (int d = 0; d < 3; ++d) x[3 + d] = Xb[(long)ro * 3 + d];   // Xo_t via Ro
    const float4 ef = ((const float4*)Eff)[e];
    x[6] = ef.x; x[7] = ef.y; x[8] = ef.z; x[9] = ef.w;

    float h1[8], h2[8], h3[8];
    #pragma unroll
    for (int j = 0; j < 8; ++j) {
        float s = sb1[j];
        #pragma unroll
        for (int i = 0; i < 10; ++i) s += x[i] * sW1[i * 8 + j];
        h1[j] = elu(s);
    }
    #pragma unroll
    for (int j = 0; j < 8; ++j) {
        float s = sb2[j];
        #pragma unroll
        for (int i = 0; i < 8; ++i) s += h1[i] * sW2[i * 8 + j];
        h2[j] = elu(s);
    }
    #pragma unroll
    for (int j = 0; j < 8; ++j) {
        float s = sb3[j];
        #pragma unroll
        for (int i = 0; i < 8; ++i) s += h2[i] * sW3[i * 8 + j];
        h3[j] = elu(s);
    }
    float s = sb4[0];
    #pragma unroll
    for (int i = 0; i < 8; ++i) s += h3[i] * sW4[i];
    out[e] = 1.0f / (1.0f + expf(-s));
}

extern "C" void kernel_launch(void* const* d_in, const int* in_sizes, int n_in,
                              void* d_out, int out_size, void* d_ws, size_t ws_size,
                              hipStream_t stream) {
    const float* X  = (const float*)d_in[0];
    const float* Ra = (const float*)d_in[1];
    const float* Ro = (const float*)d_in[2];
    const float* Ri = (const float*)d_in[3];
    const float* r1W1 = (const float*)d_in[4];  const float* r1b1 = (const float*)d_in[5];
    const float* r1W2 = (const float*)d_in[6];  const float* r1b2 = (const float*)d_in[7];
    const float* r1W3 = (const float*)d_in[8];  const float* r1b3 = (const float*)d_in[9];
    const float* r1W4 = (const float*)d_in[10]; const float* r1b4 = (const float*)d_in[11];
    const float* r2W1 = (const float*)d_in[12]; const float* r2b1 = (const float*)d_in[13];
    const float* r2W2 = (const float*)d_in[14]; const float* r2b2 = (const float*)d_in[15];
    const float* r2W3 = (const float*)d_in[16]; const float* r2b3 = (const float*)d_in[17];
    const float* r2W4 = (const float*)d_in[18]; const float* r2b4 = (const float*)d_in[19];
    const float* oW1  = (const float*)d_in[20]; const float* ob1  = (const float*)d_in[21];
    const float* oW2  = (const float*)d_in[22]; const float* ob2  = (const float*)d_in[23];
    const float* oW3  = (const float*)d_in[24]; const float* ob3  = (const float*)d_in[25];

    // workspace layout (16B-aligned segments)
    char* ws = (char*)d_ws;
    int*   ro_idx = (int*)(ws + 0);                 // 32768 ints   (128 KiB)
    int*   ri_idx = (int*)(ws + 131072);            // 32768 ints   (128 KiB)
    float* Eff    = (float*)(ws + 262144);          // 131072 f32   (512 KiB)
    float* A      = (float*)(ws + 786432);          // 32768 f32    (128 KiB)
    float* Xtil   = (float*)(ws + 917504);          // 24576 f32    ( 96 KiB)

    // nth = 4096*256 = 2^20; chunks = 2^24 -> exactly 4 outer iters, no tail
    in_idx_kernel<<<4096, 256, 0, stream>>>((const uint4*)Ro, (const uint4*)Ri,
                                            ro_idx, ri_idx, A, NTOT * 4 /* 32768 */);

    in_edge1_kernel<<<ETOT / 256, 256, 0, stream>>>(X, Ra, ro_idx, ri_idx,
                                                    r1W1, r1b1, r1W2, r1b2, r1W3, r1b3, r1W4, r1b4,
                                                    Eff, A);

    in_node_kernel<<<NTOT / 256, 256, 0, stream>>>(X, A,
                                                   oW1, ob1, oW2, ob2, oW3, ob3,
                                                   Xtil);

    in_edge2_kernel<<<ETOT / 256, 256, 0, stream>>>(Xtil, Eff, ro_idx, ri_idx,
                                                    r2W1, r2b1, r2W2, r2b2, r2W3, r2b3, r2W4, r2b4,
                                                    (float*)d_out);
}

// Round 5
// 124.494 us; speedup vs baseline: 1.1624x; 1.1624x over previous
//
#include <hip/hip_runtime.h>
#include <hip/hip_bf16.h>
#include <cstdint>

#define NBATCH 4
#define NNODE  2048
#define NEDGE  8192
#define ETOT   (NBATCH * NEDGE)   // 32768 edges total
#define NTOT   (NBATCH * NNODE)   // 8192 nodes total

typedef uint32_t u32x4 __attribute__((ext_vector_type(4)));

__device__ __forceinline__ float elu(float x) {
    return x > 0.0f ? x : expm1f(x);
}

// ---------------------------------------------------------------------------
// Kernel 1: scan the dense one-hot Ro/Ri matrices (f32), extract the column
// index of the single 1.0 per row. Non-temporal loads: the matrices are
// touch-once streams; nt bypasses L2/L3 allocation churn. Also zeroes A.
// Launch: nth = 2^20; chunks/matrix = 2^24 -> 4 outer iters of 4 loads.
// ---------------------------------------------------------------------------
__global__ void in_idx_kernel(const u32x4* __restrict__ Ro,
                              const u32x4* __restrict__ Ri,
                              int* __restrict__ ro_idx,
                              int* __restrict__ ri_idx,
                              float* __restrict__ A, int a_elems) {
    const int tid = blockIdx.x * blockDim.x + threadIdx.x;
    const int nth = gridDim.x * blockDim.x;          // 2^20

    for (int i = tid; i < a_elems; i += nth) A[i] = 0.0f;

    const int chunks = ETOT * (NNODE / 4);           // 2^24 per matrix

    #pragma unroll
    for (int m = 0; m < 2; ++m) {
        const u32x4* __restrict__ src = m ? Ri : Ro;
        int* __restrict__ dst = m ? ri_idx : ro_idx;
        for (int base = tid; base < chunks; base += 4 * nth) {
            // 4 independent non-temporal loads in flight
            const u32x4 v0 = __builtin_nontemporal_load(&src[base]);
            const u32x4 v1 = __builtin_nontemporal_load(&src[base + nth]);
            const u32x4 v2 = __builtin_nontemporal_load(&src[base + 2 * nth]);
            const u32x4 v3 = __builtin_nontemporal_load(&src[base + 3 * nth]);
            const uint32_t o0 = v0.x | v0.y | v0.z | v0.w;
            const uint32_t o1 = v1.x | v1.y | v1.z | v1.w;
            const uint32_t o2 = v2.x | v2.y | v2.z | v2.w;
            const uint32_t o3 = v3.x | v3.y | v3.z | v3.w;
            if ((o0 | o1 | o2 | o3) == 0u) continue;
            // rare path: ~1/128 of iterations
            const u32x4  vs[4] = {v0, v1, v2, v3};
            const uint32_t os[4] = {o0, o1, o2, o3};
            #pragma unroll
            for (int u = 0; u < 4; ++u) {
                if (os[u] == 0u) continue;
                const int cc = base + u * nth;
                const uint32_t w[4] = {vs[u].x, vs[u].y, vs[u].z, vs[u].w};
                #pragma unroll
                for (int k = 0; k < 4; ++k) {
                    if (w[k] != 0u) {
                        const int pos = cc * 4 + k;          // flat f32 index (< 2^26)
                        dst[pos >> 11] = pos & (NNODE - 1);
                    }
                }
            }
        }
    }
}

// ---------------------------------------------------------------------------
// Kernel 2: per-edge phi_R1 (10->8->8->8->4, ELU) + scatter-add into A.
// ---------------------------------------------------------------------------
__global__ void in_edge1_kernel(const float* __restrict__ X,    // [B,3,N]
                                const float* __restrict__ Ra,   // [B,E,4]
                                const int* __restrict__ ro_idx,
                                const int* __restrict__ ri_idx,
                                const float* __restrict__ W1, const float* __restrict__ b1,
                                const float* __restrict__ W2, const float* __restrict__ b2,
                                const float* __restrict__ W3, const float* __restrict__ b3,
                                const float* __restrict__ W4, const float* __restrict__ b4,
                                float* __restrict__ Eff,       // [B*E,4]
                                float* __restrict__ A) {       // [B*N,4]
    __shared__ float sW1[80], sb1[8], sW2[64], sb2[8], sW3[64], sb3[8], sW4[32], sb4[4];
    const int t = threadIdx.x, bs = blockDim.x;
    for (int i = t; i < 80; i += bs) sW1[i] = W1[i];
    for (int i = t; i < 8;  i += bs) sb1[i] = b1[i];
    for (int i = t; i < 64; i += bs) sW2[i] = W2[i];
    for (int i = t; i < 8;  i += bs) sb2[i] = b2[i];
    for (int i = t; i < 64; i += bs) sW3[i] = W3[i];
    for (int i = t; i < 8;  i += bs) sb3[i] = b3[i];
    for (int i = t; i < 32; i += bs) sW4[i] = W4[i];
    for (int i = t; i < 4;  i += bs) sb4[i] = b4[i];
    __syncthreads();

    const int e = blockIdx.x * blockDim.x + threadIdx.x;
    if (e >= ETOT) return;
    const int b  = e >> 13;                       // / NEDGE
    const int ro = ro_idx[e] & (NNODE - 1);       // mask: garbage -> wrong, not fault
    const int ri = ri_idx[e] & (NNODE - 1);

    float x[10];
    const float* Xb = X + (long)b * 3 * NNODE;
    #pragma unroll
    for (int d = 0; d < 3; ++d) x[d]     = Xb[d * NNODE + ro];  // Xi (receiver)
    #pragma unroll
    for (int d = 0; d < 3; ++d) x[3 + d] = Xb[d * NNODE + ri];  // Xo (sender)
    const float4 ra = ((const float4*)Ra)[e];
    x[6] = ra.x; x[7] = ra.y; x[8] = ra.z; x[9] = ra.w;

    float h1[8], h2[8], h3[8];
    #pragma unroll
    for (int j = 0; j < 8; ++j) {
        float s = sb1[j];
        #pragma unroll
        for (int i = 0; i < 10; ++i) s += x[i] * sW1[i * 8 + j];
        h1[j] = elu(s);
    }
    #pragma unroll
    for (int j = 0; j < 8; ++j) {
        float s = sb2[j];
        #pragma unroll
        for (int i = 0; i < 8; ++i) s += h1[i] * sW2[i * 8 + j];
        h2[j] = elu(s);
    }
    #pragma unroll
    for (int j = 0; j < 8; ++j) {
        float s = sb3[j];
        #pragma unroll
        for (int i = 0; i < 8; ++i) s += h2[i] * sW3[i * 8 + j];
        h3[j] = elu(s);
    }
    float* Arow = A + ((long)(b * NNODE + ri)) * 4;
    float4 eff;
    float* effp = (float*)&eff;
    #pragma unroll
    for (int j = 0; j < 4; ++j) {
        float s = sb4[j];
        #pragma unroll
        for (int i = 0; i < 8; ++i) s += h3[i] * sW4[i * 4 + j];
        effp[j] = s;
        atomicAdd(&Arow[j], s);
    }
    ((float4*)Eff)[e] = eff;
}

// ---------------------------------------------------------------------------
// Kernel 3: per-node phi_O (7->8->8->3, ELU on hidden).
// ---------------------------------------------------------------------------
__global__ void in_node_kernel(const float* __restrict__ X,     // [B,3,N]
                               const float* __restrict__ A,     // [B*N,4]
                               const float* __restrict__ W1, const float* __restrict__ b1,
                               const float* __restrict__ W2, const float* __restrict__ b2,
                               const float* __restrict__ W3, const float* __restrict__ b3,
                               float* __restrict__ Xtil) {      // [B*N,3]
    __shared__ float sW1[56], sb1[8], sW2[64], sb2[8], sW3[24], sb3[3];
    const int t = threadIdx.x, bs = blockDim.x;
    for (int i = t; i < 56; i += bs) sW1[i] = W1[i];
    for (int i = t; i < 8;  i += bs) sb1[i] = b1[i];
    for (int i = t; i < 64; i += bs) sW2[i] = W2[i];
    for (int i = t; i < 8;  i += bs) sb2[i] = b2[i];
    for (int i = t; i < 24; i += bs) sW3[i] = W3[i];
    for (int i = t; i < 3;  i += bs) sb3[i] = b3[i];
    __syncthreads();

    const int n = blockIdx.x * blockDim.x + threadIdx.x;
    if (n >= NTOT) return;
    const int b  = n >> 11;           // / NNODE
    const int nn = n & (NNODE - 1);

    float c[7];
    const float* Xb = X + (long)b * 3 * NNODE;
    #pragma unroll
    for (int d = 0; d < 3; ++d) c[d] = Xb[d * NNODE + nn];
    const float4 a4 = ((const float4*)A)[n];
    c[3] = a4.x; c[4] = a4.y; c[5] = a4.z; c[6] = a4.w;

    float h1[8], h2[8];
    #pragma unroll
    for (int j = 0; j < 8; ++j) {
        float s = sb1[j];
        #pragma unroll
        for (int i = 0; i < 7; ++i) s += c[i] * sW1[i * 8 + j];
        h1[j] = elu(s);
    }
    #pragma unroll
    for (int j = 0; j < 8; ++j) {
        float s = sb2[j];
        #pragma unroll
        for (int i = 0; i < 8; ++i) s += h1[i] * sW2[i * 8 + j];
        h2[j] = elu(s);
    }
    #pragma unroll
    for (int j = 0; j < 3; ++j) {
        float s = sb3[j];
        #pragma unroll
        for (int i = 0; i < 8; ++i) s += h2[i] * sW3[i * 3 + j];
        Xtil[(long)n * 3 + j] = s;
    }
}

// ---------------------------------------------------------------------------
// Kernel 4: per-edge phi_R2 (10->8->8->8->1, ELU) + sigmoid -> f32 out.
// ---------------------------------------------------------------------------
__global__ void in_edge2_kernel(const float* __restrict__ Xtil,  // [B*N,3]
                                const float* __restrict__ Eff,   // [B*E,4]
                                const int* __restrict__ ro_idx,
                                const int* __restrict__ ri_idx,
                                const float* __restrict__ W1, const float* __restrict__ b1,
                                const float* __restrict__ W2, const float* __restrict__ b2,
                                const float* __restrict__ W3, const float* __restrict__ b3,
                                const float* __restrict__ W4, const float* __restrict__ b4,
                                float* __restrict__ out) {       // [B*E]
    __shared__ float sW1[80], sb1[8], sW2[64], sb2[8], sW3[64], sb3[8], sW4[8], sb4[1];
    const int t = threadIdx.x, bs = blockDim.x;
    for (int i = t; i < 80; i += bs) sW1[i] = W1[i];
    for (int i = t; i < 8;  i += bs) sb1[i] = b1[i];
    for (int i = t; i < 64; i += bs) sW2[i] = W2[i];
    for (int i = t; i < 8;  i += bs) sb2[i] = b2[i];
    for (int i = t; i < 64; i += bs) sW3[i] = W3[i];
    for (int i = t; i < 8;  i += bs) sb3[i] = b3[i];
    for (int i = t; i < 8;  i += bs) sW4[i] = W4[i];
    for (int i = t; i < 1;  i += bs) sb4[i] = b4[i];
    __syncthreads();

    const int e = blockIdx.x * blockDim.x + threadIdx.x;
    if (e >= ETOT) return;
    const int b  = e >> 13;
    const int ro = ro_idx[e] & (NNODE - 1);
    const int ri = ri_idx[e] & (NNODE - 1);

    float x[10];
    const float* Xb = Xtil + (long)b * NNODE * 3;
    #pragma unroll
    for (int d = 0; d < 3; ++d) x[d]     = Xb[(long)ri * 3 + d];   // Xi_t via Ri
    #pragma unroll
    for (int d = 0; d < 3; ++d) x[3 + d] = Xb[(long)ro * 3 + d];   // Xo_t via Ro
    const float4 ef = ((const float4*)Eff)[e];
    x[6] = ef.x; x[7] = ef.y; x[8] = ef.z; x[9] = ef.w;

    float h1[8], h2[8], h3[8];
    #pragma unroll
    for (int j = 0; j < 8; ++j) {
        float s = sb1[j];
        #pragma unroll
        for (int i = 0; i < 10; ++i) s += x[i] * sW1[i * 8 + j];
        h1[j] = elu(s);
    }
    #pragma unroll
    for (int j = 0; j < 8; ++j) {
        float s = sb2[j];
        #pragma unroll
        for (int i = 0; i < 8; ++i) s += h1[i] * sW2[i * 8 + j];
        h2[j] = elu(s);
    }
    #pragma unroll
    for (int j = 0; j < 8; ++j) {
        float s = sb3[j];
        #pragma unroll
        for (int i = 0; i < 8; ++i) s += h2[i] * sW3[i * 8 + j];
        h3[j] = elu(s);
    }
    float s = sb4[0];
    #pragma unroll
    for (int i = 0; i < 8; ++i) s += h3[i] * sW4[i];
    out[e] = 1.0f / (1.0f + expf(-s));
}

extern "C" void kernel_launch(void* const* d_in, const int* in_sizes, int n_in,
                              void* d_out, int out_size, void* d_ws, size_t ws_size,
                              hipStream_t stream) {
    const float* X  = (const float*)d_in[0];
    const float* Ra = (const float*)d_in[1];
    const float* Ro = (const float*)d_in[2];
    const float* Ri = (const float*)d_in[3];
    const float* r1W1 = (const float*)d_in[4];  const float* r1b1 = (const float*)d_in[5];
    const float* r1W2 = (const float*)d_in[6];  const float* r1b2 = (const float*)d_in[7];
    const float* r1W3 = (const float*)d_in[8];  const float* r1b3 = (const float*)d_in[9];
    const float* r1W4 = (const float*)d_in[10]; const float* r1b4 = (const float*)d_in[11];
    const float* r2W1 = (const float*)d_in[12]; const float* r2b1 = (const float*)d_in[13];
    const float* r2W2 = (const float*)d_in[14]; const float* r2b2 = (const float*)d_in[15];
    const float* r2W3 = (const float*)d_in[16]; const float* r2b3 = (const float*)d_in[17];
    const float* r2W4 = (const float*)d_in[18]; const float* r2b4 = (const float*)d_in[19];
    const float* oW1  = (const float*)d_in[20]; const float* ob1  = (const float*)d_in[21];
    const float* oW2  = (const float*)d_in[22]; const float* ob2  = (const float*)d_in[23];
    const float* oW3  = (const float*)d_in[24]; const float* ob3  = (const float*)d_in[25];

    // workspace layout (16B-aligned segments)
    char* ws = (char*)d_ws;
    int*   ro_idx = (int*)(ws + 0);                 // 32768 ints   (128 KiB)
    int*   ri_idx = (int*)(ws + 131072);            // 32768 ints   (128 KiB)
    float* Eff    = (float*)(ws + 262144);          // 131072 f32   (512 KiB)
    float* A      = (float*)(ws + 786432);          // 32768 f32    (128 KiB)
    float* Xtil   = (float*)(ws + 917504);          // 24576 f32    ( 96 KiB)

    // nth = 4096*256 = 2^20; chunks = 2^24 -> exactly 4 outer iters, no tail
    in_idx_kernel<<<4096, 256, 0, stream>>>((const u32x4*)Ro, (const u32x4*)Ri,
                                            ro_idx, ri_idx, A, NTOT * 4 /* 32768 */);

    in_edge1_kernel<<<ETOT / 256, 256, 0, stream>>>(X, Ra, ro_idx, ri_idx,
                                                    r1W1, r1b1, r1W2, r1b2, r1W3, r1b3, r1W4, r1b4,
                                                    Eff, A);

    in_node_kernel<<<NTOT / 256, 256, 0, stream>>>(X, A,
                                                   oW1, ob1, oW2, ob2, oW3, ob3,
                                                   Xtil);

    in_edge2_kernel<<<ETOT / 256, 256, 0, stream>>>(Xtil, Eff, ro_idx, ri_idx,
                                                    r2W1, r2b1, r2W2, r2b2, r2W3, r2b3, r2W4, r2b4,
                                                    (float*)d_out);
}

// Round 6
// 75.869 us; speedup vs baseline: 1.9073x; 1.6409x over previous
//
#include <hip/hip_runtime.h>
#include <hip/hip_bf16.h>
#include <cstdint>

#define NBATCH 4
#define NNODE  2048
#define NEDGE  8192
#define ETOT   (NBATCH * NEDGE)   // 32768 edges total
#define NTOT   (NBATCH * NNODE)   // 8192 nodes total

typedef uint32_t u32x4 __attribute__((ext_vector_type(4)));

__device__ __forceinline__ float elu(float x) {
    return x > 0.0f ? x : expm1f(x);
}

// ---------------------------------------------------------------------------
// Kernel 1: wave-per-row early-exit scan of the one-hot Ro/Ri matrices.
// Each wave owns one row (2048 f32 = 8 chunks of 64 lanes x 16B); it reads
// chunk-by-chunk and breaks at the first chunk containing the 1.0 (ballot is
// wave-uniform). Expected traffic: 4.5/8 of each row (~288 MiB total).
// nt loads: touch-once stream, bypass L2/L3 allocation. Also zeroes A.
// ---------------------------------------------------------------------------
__global__ void in_idx_kernel(const u32x4* __restrict__ Ro,
                              const u32x4* __restrict__ Ri,
                              int* __restrict__ ro_idx,
                              int* __restrict__ ri_idx,
                              float* __restrict__ A, int a_elems) {
    const int gtid = blockIdx.x * blockDim.x + threadIdx.x;
    if (gtid < a_elems) A[gtid] = 0.0f;

    const int wid  = gtid >> 6;           // global wave id = row id
    const int lane = threadIdx.x & 63;
    const int nrows = 2 * ETOT;           // 65536 (Ro rows then Ri rows)
    if (wid >= nrows) return;

    const bool second = (wid >= ETOT);
    const int  row    = second ? wid - ETOT : wid;
    const u32x4* __restrict__ src = (second ? Ri : Ro) + (size_t)row * (NNODE / 4);
    int* __restrict__ dst = second ? ri_idx : ro_idx;

    #pragma unroll
    for (int c = 0; c < NNODE / 256; ++c) {            // 8 chunks
        const u32x4 v = __builtin_nontemporal_load(&src[c * 64 + lane]);
        const uint32_t o = v.x | v.y | v.z | v.w;
        const unsigned long long found = __ballot(o != 0u);
        if (found) {
            if (o) {
                const int base = c * 256 + lane * 4;
                if      (v.x) dst[row] = base;
                else if (v.y) dst[row] = base + 1;
                else if (v.z) dst[row] = base + 2;
                else          dst[row] = base + 3;
            }
            break;   // ballot result is wave-uniform -> uniform exit
        }
    }
}

// ---------------------------------------------------------------------------
// Kernel 2: per-edge phi_R1 (10->8->8->8->4, ELU) + scatter-add into A.
// ---------------------------------------------------------------------------
__global__ void in_edge1_kernel(const float* __restrict__ X,    // [B,3,N]
                                const float* __restrict__ Ra,   // [B,E,4]
                                const int* __restrict__ ro_idx,
                                const int* __restrict__ ri_idx,
                                const float* __restrict__ W1, const float* __restrict__ b1,
                                const float* __restrict__ W2, const float* __restrict__ b2,
                                const float* __restrict__ W3, const float* __restrict__ b3,
                                const float* __restrict__ W4, const float* __restrict__ b4,
                                float* __restrict__ Eff,       // [B*E,4]
                                float* __restrict__ A) {       // [B*N,4]
    __shared__ float sW1[80], sb1[8], sW2[64], sb2[8], sW3[64], sb3[8], sW4[32], sb4[4];
    const int t = threadIdx.x, bs = blockDim.x;
    for (int i = t; i < 80; i += bs) sW1[i] = W1[i];
    for (int i = t; i < 8;  i += bs) sb1[i] = b1[i];
    for (int i = t; i < 64; i += bs) sW2[i] = W2[i];
    for (int i = t; i < 8;  i += bs) sb2[i] = b2[i];
    for (int i = t; i < 64; i += bs) sW3[i] = W3[i];
    for (int i = t; i < 8;  i += bs) sb3[i] = b3[i];
    for (int i = t; i < 32; i += bs) sW4[i] = W4[i];
    for (int i = t; i < 4;  i += bs) sb4[i] = b4[i];
    __syncthreads();

    const int e = blockIdx.x * blockDim.x + threadIdx.x;
    if (e >= ETOT) return;
    const int b  = e >> 13;                       // / NEDGE
    const int ro = ro_idx[e] & (NNODE - 1);       // mask: garbage -> wrong, not fault
    const int ri = ri_idx[e] & (NNODE - 1);

    float x[10];
    const float* Xb = X + (long)b * 3 * NNODE;
    #pragma unroll
    for (int d = 0; d < 3; ++d) x[d]     = Xb[d * NNODE + ro];  // Xi (receiver)
    #pragma unroll
    for (int d = 0; d < 3; ++d) x[3 + d] = Xb[d * NNODE + ri];  // Xo (sender)
    const float4 ra = ((const float4*)Ra)[e];
    x[6] = ra.x; x[7] = ra.y; x[8] = ra.z; x[9] = ra.w;

    float h1[8], h2[8], h3[8];
    #pragma unroll
    for (int j = 0; j < 8; ++j) {
        float s = sb1[j];
        #pragma unroll
        for (int i = 0; i < 10; ++i) s += x[i] * sW1[i * 8 + j];
        h1[j] = elu(s);
    }
    #pragma unroll
    for (int j = 0; j < 8; ++j) {
        float s = sb2[j];
        #pragma unroll
        for (int i = 0; i < 8; ++i) s += h1[i] * sW2[i * 8 + j];
        h2[j] = elu(s);
    }
    #pragma unroll
    for (int j = 0; j < 8; ++j) {
        float s = sb3[j];
        #pragma unroll
        for (int i = 0; i < 8; ++i) s += h2[i] * sW3[i * 8 + j];
        h3[j] = elu(s);
    }
    float* Arow = A + ((long)(b * NNODE + ri)) * 4;
    float4 eff;
    float* effp = (float*)&eff;
    #pragma unroll
    for (int j = 0; j < 4; ++j) {
        float s = sb4[j];
        #pragma unroll
        for (int i = 0; i < 8; ++i) s += h3[i] * sW4[i * 4 + j];
        effp[j] = s;
        atomicAdd(&Arow[j], s);
    }
    ((float4*)Eff)[e] = eff;
}

// ---------------------------------------------------------------------------
// Kernel 3: per-node phi_O (7->8->8->3, ELU on hidden).
// ---------------------------------------------------------------------------
__global__ void in_node_kernel(const float* __restrict__ X,     // [B,3,N]
                               const float* __restrict__ A,     // [B*N,4]
                               const float* __restrict__ W1, const float* __restrict__ b1,
                               const float* __restrict__ W2, const float* __restrict__ b2,
                               const float* __restrict__ W3, const float* __restrict__ b3,
                               float* __restrict__ Xtil) {      // [B*N,3]
    __shared__ float sW1[56], sb1[8], sW2[64], sb2[8], sW3[24], sb3[3];
    const int t = threadIdx.x, bs = blockDim.x;
    for (int i = t; i < 56; i += bs) sW1[i] = W1[i];
    for (int i = t; i < 8;  i += bs) sb1[i] = b1[i];
    for (int i = t; i < 64; i += bs) sW2[i] = W2[i];
    for (int i = t; i < 8;  i += bs) sb2[i] = b2[i];
    for (int i = t; i < 24; i += bs) sW3[i] = W3[i];
    for (int i = t; i < 3;  i += bs) sb3[i] = b3[i];
    __syncthreads();

    const int n = blockIdx.x * blockDim.x + threadIdx.x;
    if (n >= NTOT) return;
    const int b  = n >> 11;           // / NNODE
    const int nn = n & (NNODE - 1);

    float c[7];
    const float* Xb = X + (long)b * 3 * NNODE;
    #pragma unroll
    for (int d = 0; d < 3; ++d) c[d] = Xb[d * NNODE + nn];
    const float4 a4 = ((const float4*)A)[n];
    c[3] = a4.x; c[4] = a4.y; c[5] = a4.z; c[6] = a4.w;

    float h1[8], h2[8];
    #pragma unroll
    for (int j = 0; j < 8; ++j) {
        float s = sb1[j];
        #pragma unroll
        for (int i = 0; i < 7; ++i) s += c[i] * sW1[i * 8 + j];
        h1[j] = elu(s);
    }
    #pragma unroll
    for (int j = 0; j < 8; ++j) {
        float s = sb2[j];
        #pragma unroll
        for (int i = 0; i < 8; ++i) s += h1[i] * sW2[i * 8 + j];
        h2[j] = elu(s);
    }
    #pragma unroll
    for (int j = 0; j < 3; ++j) {
        float s = sb3[j];
        #pragma unroll
        for (int i = 0; i < 8; ++i) s += h2[i] * sW3[i * 3 + j];
        Xtil[(long)n * 3 + j] = s;
    }
}

// ---------------------------------------------------------------------------
// Kernel 4: per-edge phi_R2 (10->8->8->8->1, ELU) + sigmoid -> f32 out.
// ---------------------------------------------------------------------------
__global__ void in_edge2_kernel(const float* __restrict__ Xtil,  // [B*N,3]
                                const float* __restrict__ Eff,   // [B*E,4]
                                const int* __restrict__ ro_idx,
                                const int* __restrict__ ri_idx,
                                const float* __restrict__ W1, const float* __restrict__ b1,
                                const float* __restrict__ W2, const float* __restrict__ b2,
                                const float* __restrict__ W3, const float* __restrict__ b3,
                                const float* __restrict__ W4, const float* __restrict__ b4,
                                float* __restrict__ out) {       // [B*E]
    __shared__ float sW1[80], sb1[8], sW2[64], sb2[8], sW3[64], sb3[8], sW4[8], sb4[1];
    const int t = threadIdx.x, bs = blockDim.x;
    for (int i = t; i < 80; i += bs) sW1[i] = W1[i];
    for (int i = t; i < 8;  i += bs) sb1[i] = b1[i];
    for (int i = t; i < 64; i += bs) sW2[i] = W2[i];
    for (int i = t; i < 8;  i += bs) sb2[i] = b2[i];
    for (int i = t; i < 64; i += bs) sW3[i] = W3[i];
    for (int i = t; i < 8;  i += bs) sb3[i] = b3[i];
    for (int i = t; i < 8;  i += bs) sW4[i] = W4[i];
    for (int i = t; i < 1;  i += bs) sb4[i] = b4[i];
    __syncthreads();

    const int e = blockIdx.x * blockDim.x + threadIdx.x;
    if (e >= ETOT) return;
    const int b  = e >> 13;
    const int ro = ro_idx[e] & (NNODE - 1);
    const int ri = ri_idx[e] & (NNODE - 1);

    float x[10];
    const float* Xb = Xtil + (long)b * NNODE * 3;
    #pragma unroll
    for (int d = 0; d < 3; ++d) x[d]     = Xb[(long)ri * 3 + d];   // Xi_t via Ri
    #pragma unroll
    for (int d = 0; d < 3; ++d) x[3 + d] = Xb[(long)ro * 3 + d];   // Xo_t via Ro
    const float4 ef = ((const float4*)Eff)[e];
    x[6] = ef.x; x[7] = ef.y; x[8] = ef.z; x[9] = ef.w;

    float h1[8], h2[8], h3[8];
    #pragma unroll
    for (int j = 0; j < 8; ++j) {
        float s = sb1[j];
        #pragma unroll
        for (int i = 0; i < 10; ++i) s += x[i] * sW1[i * 8 + j];
        h1[j] = elu(s);
    }
    #pragma unroll
    for (int j = 0; j < 8; ++j) {
        float s = sb2[j];
        #pragma unroll
        for (int i = 0; i < 8; ++i) s += h1[i] * sW2[i * 8 + j];
        h2[j] = elu(s);
    }
    #pragma unroll
    for (int j = 0; j < 8; ++j) {
        float s = sb3[j];
        #pragma unroll
        for (int i = 0; i < 8; ++i) s += h2[i] * sW3[i * 8 + j];
        h3[j] = elu(s);
    }
    float s = sb4[0];
    #pragma unroll
    for (int i = 0; i < 8; ++i) s += h3[i] * sW4[i];
    out[e] = 1.0f / (1.0f + expf(-s));
}

extern "C" void kernel_launch(void* const* d_in, const int* in_sizes, int n_in,
                              void* d_out, int out_size, void* d_ws, size_t ws_size,
                              hipStream_t stream) {
    const float* X  = (const float*)d_in[0];
    const float* Ra = (const float*)d_in[1];
    const float* Ro = (const float*)d_in[2];
    const float* Ri = (const float*)d_in[3];
    const float* r1W1 = (const float*)d_in[4];  const float* r1b1 = (const float*)d_in[5];
    const float* r1W2 = (const float*)d_in[6];  const float* r1b2 = (const float*)d_in[7];
    const float* r1W3 = (const float*)d_in[8];  const float* r1b3 = (const float*)d_in[9];
    const float* r1W4 = (const float*)d_in[10]; const float* r1b4 = (const float*)d_in[11];
    const float* r2W1 = (const float*)d_in[12]; const float* r2b1 = (const float*)d_in[13];
    const float* r2W2 = (const float*)d_in[14]; const float* r2b2 = (const float*)d_in[15];
    const float* r2W3 = (const float*)d_in[16]; const float* r2b3 = (const float*)d_in[17];
    const float* r2W4 = (const float*)d_in[18]; const float* r2b4 = (const float*)d_in[19];
    const float* oW1  = (const float*)d_in[20]; const float* ob1  = (const float*)d_in[21];
    const float* oW2  = (const float*)d_in[22]; const float* ob2  = (const float*)d_in[23];
    const float* oW3  = (const float*)d_in[24]; const float* ob3  = (const float*)d_in[25];

    // workspace layout (16B-aligned segments)
    char* ws = (char*)d_ws;
    int*   ro_idx = (int*)(ws + 0);                 // 32768 ints   (128 KiB)
    int*   ri_idx = (int*)(ws + 131072);            // 32768 ints   (128 KiB)
    float* Eff    = (float*)(ws + 262144);          // 131072 f32   (512 KiB)
    float* A      = (float*)(ws + 786432);          // 32768 f32    (128 KiB)
    float* Xtil   = (float*)(ws + 917504);          // 24576 f32    ( 96 KiB)

    // one wave per row: 2*ETOT rows = 65536 waves = 4,194,304 threads
    in_idx_kernel<<<(2 * ETOT * 64) / 256, 256, 0, stream>>>(
        (const u32x4*)Ro, (const u32x4*)Ri, ro_idx, ri_idx, A, NTOT * 4 /* 32768 */);

    in_edge1_kernel<<<ETOT / 256, 256, 0, stream>>>(X, Ra, ro_idx, ri_idx,
                                                    r1W1, r1b1, r1W2, r1b2, r1W3, r1b3, r1W4, r1b4,
                                                    Eff, A);

    in_node_kernel<<<NTOT / 256, 256, 0, stream>>>(X, A,
                                                   oW1, ob1, oW2, ob2, oW3, ob3,
                                                   Xtil);

    in_edge2_kernel<<<ETOT / 256, 256, 0, stream>>>(Xtil, Eff, ro_idx, ri_idx,
                                                    r2W1, r2b1, r2W2, r2b2, r2W3, r2b3, r2W4, r2b4,
                                                    (float*)d_out);
}